// Round 7
// baseline (240.495 us; speedup 1.0000x reference)
//
#include <hip/hip_runtime.h>

#define BB 4
#define QQ 256
#define VV 2048
#define HH 512
#define UU 128

// tanh arg scale folded into projections: C2E = 2*log2(e); exp(x)=exp2(x*LOG2E)
#define C2E   2.8853900817779268f
#define LOG2E 1.4426950408889634f

__device__ __forceinline__ void fma4(float4& a, float s, const float4& w) {
    a.x = fmaf(s, w.x, a.x);
    a.y = fmaf(s, w.y, a.y);
    a.z = fmaf(s, w.z, a.z);
    a.w = fmaf(s, w.w, a.w);
}
__device__ __forceinline__ float2 rcp2(float2 x) {
    return make_float2(__builtin_amdgcn_rcpf(x.x), __builtin_amdgcn_rcpf(x.y));
}
__device__ __forceinline__ float2 mul2(float2 a, float2 b) { return make_float2(a.x*b.x, a.y*b.y); }
__device__ __forceinline__ float2 muls(float2 a, float s)  { return make_float2(a.x*s, a.y*s); }
__device__ __forceinline__ float2 fma2(float2 a, float2 b, float2 c) {
    return make_float2(fmaf(a.x, b.x, c.x), fmaf(a.y, b.y, c.y));
}
__device__ __forceinline__ float2 fmas(float2 a, float s, float2 c) {
    return make_float2(fmaf(a.x, s, c.x), fmaf(a.y, s, c.y));
}
__device__ __forceinline__ float2 fmass(float2 a, float s, float c) {
    return make_float2(fmaf(a.x, s, c), fmaf(a.y, s, c));
}

// ---------------------------------------------------------------------------
// Projection GEMM -> EXPONENTIATED transposed output:
//   E[u][r] = exp2( C2E * sum_h A[r][h]*W[h][u] )
// (exp2 hoisted out of fused's inner loop: exp2(pq+pv) = Eq*Ev.)
// 16 rows x 128 u per block, BK=32. grid = 512 (values) + 64 (queries).
// values out: interleaved pvT4: (b,g,v,j) at b*UU*VV + (g*VV+v)*4 + j.
// queries out: pqT[b][u][QQ]. Block 0 also zeroes denom[1024].
// ---------------------------------------------------------------------------
__global__ __launch_bounds__(256) void proj_kernel(const float* __restrict__ queries,
                                                   const float* __restrict__ values,
                                                   const float* __restrict__ w1,
                                                   const float* __restrict__ w2,
                                                   float* __restrict__ pqT,
                                                   float* __restrict__ pvT,
                                                   float* __restrict__ denom) {
    __shared__ float As[32][18];     // [k][row]
    __shared__ float Ws[32 * 128];   // [k][u]
    __shared__ float Ls[128][17];    // [u][row] epilogue transpose
    const int bid = blockIdx.x;
    const int tid = threadIdx.x;
    if (bid == 0) *(float4*)&denom[tid * 4] = make_float4(0.f, 0.f, 0.f, 0.f);

    const bool isv = (bid < 512);
    const float* A; const float* W; int b, r0;
    if (isv) {                             // values: 8192 rows
        b = bid >> 7; r0 = (bid & 127) * 16;
        A = values + ((size_t)(b * VV + r0)) * HH;  W = w2;
    } else {                               // queries: 1024 rows
        const int q = bid - 512;
        b = q >> 4; r0 = (q & 15) * 16;
        A = queries + ((size_t)(b * QQ + r0)) * HH; W = w1;
    }

    const int tx = tid & 31;         // u-group: u = tx*4 .. tx*4+3
    const int ty = tid >> 5;         // row-pair: rows 2ty, 2ty+1
    float4 acc0 = make_float4(0.f, 0.f, 0.f, 0.f);
    float4 acc1 = make_float4(0.f, 0.f, 0.f, 0.f);

    for (int k0 = 0; k0 < HH; k0 += 32) {
        if (tid < 128) {             // A tile: 16 rows x 32 k, store transposed
            const int r = tid >> 3, kk4 = (tid & 7) * 4;
            const float4 a = *(const float4*)&A[(size_t)r * HH + k0 + kk4];
            As[kk4 + 0][r] = a.x; As[kk4 + 1][r] = a.y;
            As[kk4 + 2][r] = a.z; As[kk4 + 3][r] = a.w;
        }
#pragma unroll
        for (int t = 0; t < 4; t++) {  // W tile: 32 k x 128 u
            const int f = tid + t * 256;
            const int kk = f >> 5, u4 = (f & 31) * 4;
            *(float4*)&Ws[kk * 128 + u4] = *(const float4*)&W[(size_t)(k0 + kk) * UU + u4];
        }
        __syncthreads();
#pragma unroll
        for (int kk = 0; kk < 32; kk++) {
            const float2 a = *(const float2*)&As[kk][ty * 2];   // broadcast
            const float4 w = *(const float4*)&Ws[kk * 128 + tx * 4];
            fma4(acc0, a.x, w);
            fma4(acc1, a.y, w);
        }
        __syncthreads();
    }
    {
        const float a0[4] = {acc0.x, acc0.y, acc0.z, acc0.w};
        const float a1[4] = {acc1.x, acc1.y, acc1.z, acc1.w};
#pragma unroll
        for (int i = 0; i < 4; i++) {
            Ls[tx * 4 + i][ty * 2 + 0] = __builtin_amdgcn_exp2f(a0[i] * C2E);
            Ls[tx * 4 + i][ty * 2 + 1] = __builtin_amdgcn_exp2f(a1[i] * C2E);
        }
    }
    __syncthreads();
    if (isv) {
        float* Ob = pvT + (size_t)b * UU * VV;
#pragma unroll
        for (int t = 0; t < 2; t++) {
            const int idx = tid + t * 256;
            const int g = idx >> 4, r = idx & 15;
            float4 o;
            o.x = Ls[4 * g + 0][r]; o.y = Ls[4 * g + 1][r];
            o.z = Ls[4 * g + 2][r]; o.w = Ls[4 * g + 3][r];
            *(float4*)&Ob[((size_t)g * VV + r0 + r) * 4] = o;
        }
    } else {
        float* O = pqT + (size_t)b * UU * QQ + r0;
        const int uu = tid >> 1, half = (tid & 1) * 8;
        float4 o0, o1;
        o0.x = Ls[uu][half + 0]; o0.y = Ls[uu][half + 1];
        o0.z = Ls[uu][half + 2]; o0.w = Ls[uu][half + 3];
        o1.x = Ls[uu][half + 4]; o1.y = Ls[uu][half + 5];
        o1.z = Ls[uu][half + 6]; o1.w = Ls[uu][half + 7];
        float* dst = O + (size_t)uu * QQ + half;
        *(float4*)dst = o0;
        *(float4*)(dst + 4) = o1;
    }
}

// ---------------------------------------------------------------------------
// Fused scores+softmax-numerator+partial-out. grid = 4b*32qb*8vs = 1024,
// 512 threads (8 waves).
// Phase A: exp-product form — e = Eq*Ev, 1+e fused as one FMA; grouped-rcp
//   over 4 u: sum w_i/(1+e_i) = (nab*pcd + ncd*pab) / (pab*pcd).
//   Only 2 trans per (4u,2q) vs 10 in R6. u-range split across thread halves.
// Phase B: q-pair split across the 4 half-waves (all 256 v each, values rows
//   L1-broadcast); plain stores to private slab[vs]; no cross reduce.
// ---------------------------------------------------------------------------
__global__ __launch_bounds__(512, 8) void fused_kernel(const float* __restrict__ pqT,
                                                       const float* __restrict__ pvT,
                                                       const float* __restrict__ vvec,
                                                       const float* __restrict__ values,
                                                       float* __restrict__ slab,
                                                       float* __restrict__ denom) {
    __shared__ float att[256][8];    // [v][q] 8 KB, persists A->B
    __shared__ float cbuf[256 * 8];  // 8 KB phase-A u-half combine
    __shared__ float wred[4][8];
    const int tid = threadIdx.x;
    const int bid = blockIdx.x;
    const int vs = bid & 7, qb = (bid >> 3) & 31, b = bid >> 8;
    const int qbase = qb * 8, vbase = vs * 256;

    // ---- Phase A ----
    const int vloc = tid & 255, uh = tid >> 8;      // uh wave-uniform
    const int v = vbase + vloc;

    float vsum = 0.0f;
#pragma unroll
    for (int u4 = 0; u4 < UU; u4 += 4) {
        const float4 t = *(const float4*)&vvec[u4];
        vsum += t.x + t.y + t.z + t.w;
    }

    const float* pv4p = pvT + (size_t)b * UU * VV + (size_t)v * 4;   // Ev
    const float* pqp  = pqT + (size_t)b * UU * QQ + qbase;           // Eq, uniform

    float2 acc[4];
#pragma unroll
    for (int p = 0; p < 4; p++) acc[p] = make_float2(0.f, 0.f);

    for (int g = 0; g < 16; g++) {
        const int G = uh * 16 + g;                  // global u-group
        const float4 ev = *(const float4*)&pv4p[(size_t)G * VV * 4];
        const float4 wq = *(const float4*)&vvec[G * 4];      // uniform
        const float w0 = 2.f * wq.x, w1 = 2.f * wq.y;
        const float w2 = 2.f * wq.z, w3 = 2.f * wq.w;
        const int u0 = G * 4;
#pragma unroll
        for (int p = 0; p < 4; p++) {
            const float2 qa = *(const float2*)&pqp[(size_t)(u0 + 0) * QQ + 2 * p];
            const float2 qb2 = *(const float2*)&pqp[(size_t)(u0 + 1) * QQ + 2 * p];
            const float2 qc = *(const float2*)&pqp[(size_t)(u0 + 2) * QQ + 2 * p];
            const float2 qd = *(const float2*)&pqp[(size_t)(u0 + 3) * QQ + 2 * p];
            const float2 a1 = fmass(qa, ev.x, 1.0f);   // 1 + Eq*Ev
            const float2 b1 = fmass(qb2, ev.y, 1.0f);
            const float2 c1 = fmass(qc, ev.z, 1.0f);
            const float2 d1 = fmass(qd, ev.w, 1.0f);
            const float2 pab = mul2(a1, b1), pcd = mul2(c1, d1);
            const float2 nab = fmas(a1, w1, muls(b1, w0));   // w0*b1 + w1*a1
            const float2 ncd = fmas(c1, w3, muls(d1, w2));
            const float2 num = fma2(nab, pcd, mul2(ncd, pab));
            const float2 den = mul2(pab, pcd);
            acc[p] = fma2(num, rcp2(den), acc[p]);
        }
    }

    // combine u-halves: upper half -> LDS, lower half finishes
    if (uh == 1) {
#pragma unroll
        for (int p = 0; p < 4; p++)
            *(float2*)&cbuf[vloc * 8 + 2 * p] = acc[p];
    }
    __syncthreads();
    if (uh == 0) {
#pragma unroll
        for (int p = 0; p < 4; p++) {
            const float2 hi = *(const float2*)&cbuf[vloc * 8 + 2 * p];
            float2 e;
            e.x = __builtin_amdgcn_exp2f((vsum - (acc[p].x + hi.x)) * LOG2E);
            e.y = __builtin_amdgcn_exp2f((vsum - (acc[p].y + hi.y)) * LOG2E);
            att[vloc][2 * p + 0] = e.x;
            att[vloc][2 * p + 1] = e.y;
            acc[p] = e;
        }
#pragma unroll
        for (int off = 1; off < 64; off <<= 1) {
#pragma unroll
            for (int p = 0; p < 4; p++) {
                acc[p].x += __shfl_xor(acc[p].x, off, 64);
                acc[p].y += __shfl_xor(acc[p].y, off, 64);
            }
        }
        if ((tid & 63) == 0) {
            const int w = tid >> 6;   // 0..3
#pragma unroll
            for (int p = 0; p < 4; p++) {
                wred[w][2 * p + 0] = acc[p].x;
                wred[w][2 * p + 1] = acc[p].y;
            }
        }
    }
    __syncthreads();
    if (tid < 8)
        atomicAdd(&denom[b * QQ + qbase + tid],
                  wred[0][tid] + wred[1][tid] + wred[2][tid] + wred[3][tid]);

    // ---- Phase B: q-pair split across the 4 half-waves, all 256 v each ----
    const int hg = tid & 127, sel = tid >> 7;       // sel wave-uniform
    const int q0 = sel * 2;
    const int h0 = hg * 4;
    const float* vp = values + ((size_t)(b * VV + vbase)) * HH + h0;

    float4 o0 = make_float4(0.f, 0.f, 0.f, 0.f);
    float4 o1 = make_float4(0.f, 0.f, 0.f, 0.f);

#pragma unroll 4
    for (int vv = 0; vv < 256; vv++) {
        const float4 w = *(const float4*)&vp[(size_t)vv * HH];
        const float2 a = *(const float2*)&att[vv][q0];   // broadcast
        fma4(o0, a.x, w);
        fma4(o1, a.y, w);
    }

    float* sp = slab + (size_t)vs * (BB * QQ * HH);
    *(float4*)&sp[((size_t)(b * QQ + qbase + q0 + 0)) * HH + h0] = o0;
    *(float4*)&sp[((size_t)(b * QQ + qbase + q0 + 1)) * HH + h0] = o1;
}

// ---------------------------------------------------------------------------
// out = (sum of 8 slabs) * rcp(denom[row]). 131072 float4s, grid 512.
// ---------------------------------------------------------------------------
__global__ __launch_bounds__(256) void reduce_kernel(const float* __restrict__ slab,
                                                     const float* __restrict__ denom,
                                                     float* __restrict__ out) {
    const int i = blockIdx.x * 256 + threadIdx.x;    // float4 index
    const float r = __builtin_amdgcn_rcpf(denom[i >> 7]);
    const float4* s4 = (const float4*)slab;
    float4 s = s4[i];
#pragma unroll
    for (int k = 1; k < 8; k++) {
        const float4 p = s4[(size_t)k * (BB * QQ * HH / 4) + i];
        s.x += p.x; s.y += p.y; s.z += p.z; s.w += p.w;
    }
    s.x *= r; s.y *= r; s.z *= r; s.w *= r;
    ((float4*)out)[i] = s;
}

// ---------------------------------------------------------------------------
extern "C" void kernel_launch(void* const* d_in, const int* in_sizes, int n_in,
                              void* d_out, int out_size, void* d_ws, size_t ws_size,
                              hipStream_t stream) {
    const float* queries = (const float*)d_in[0];  // [B,Q,H]
    const float* values  = (const float*)d_in[1];  // [B,V,H]
    const float* w1      = (const float*)d_in[2];  // [H,U]
    const float* w2      = (const float*)d_in[3];  // [H,U]
    const float* vvec    = (const float*)d_in[4];  // [U]
    float* out = (float*)d_out;

    // ws (floats): pqT[131072] | pvT[1048576] | denom[1024] | slab[8*524288]
    float* ws    = (float*)d_ws;
    float* pqT   = ws;
    float* pvT   = pqT + BB * UU * QQ;
    float* denom = pvT + (size_t)BB * UU * VV;
    float* slab  = denom + BB * QQ;

    proj_kernel<<<512 + 64, 256, 0, stream>>>(queries, values, w1, w2, pqT, pvT, denom);
    fused_kernel<<<BB * (QQ / 8) * (VV / 256), 512, 0, stream>>>(pqT, pvT, vvec, values, slab, denom);
    reduce_kernel<<<(BB * QQ * HH) / 4 / 256, 256, 0, stream>>>(slab, denom, out);
}

// Round 8
// 217.433 us; speedup vs baseline: 1.1061x; 1.1061x over previous
//
#include <hip/hip_runtime.h>

#define BB 4
#define QQ 256
#define VV 2048
#define HH 512
#define UU 128

// tanh arg scale folded into projections: C2E = 2*log2(e); exp(x)=exp2(x*LOG2E)
#define C2E   2.8853900817779268f
#define LOG2E 1.4426950408889634f

__device__ __forceinline__ void fma4(float4& a, float s, const float4& w) {
    a.x = fmaf(s, w.x, a.x);
    a.y = fmaf(s, w.y, a.y);
    a.z = fmaf(s, w.z, a.z);
    a.w = fmaf(s, w.w, a.w);
}
__device__ __forceinline__ float2 rcp2(float2 x) {
    return make_float2(__builtin_amdgcn_rcpf(x.x), __builtin_amdgcn_rcpf(x.y));
}
__device__ __forceinline__ float2 mul2(float2 a, float2 b) { return make_float2(a.x*b.x, a.y*b.y); }
__device__ __forceinline__ float2 muls(float2 a, float s)  { return make_float2(a.x*s, a.y*s); }
__device__ __forceinline__ float2 fma2(float2 a, float2 b, float2 c) {
    return make_float2(fmaf(a.x, b.x, c.x), fmaf(a.y, b.y, c.y));
}
__device__ __forceinline__ float2 fmas(float2 a, float s, float2 c) {
    return make_float2(fmaf(a.x, s, c.x), fmaf(a.y, s, c.y));
}
__device__ __forceinline__ float2 fmass(float2 a, float s, float c) {
    return make_float2(fmaf(a.x, s, c), fmaf(a.y, s, c));
}

// ---------------------------------------------------------------------------
// Projection GEMM -> EXPONENTIATED transposed output:
//   E[u][r] = exp2( C2E * sum_h A[r][h]*W[h][u] )
// (exp2 hoisted out of fused's inner loop: exp2(pq+pv) = Eq*Ev.)
// 16 rows x 128 u per block, BK=32. grid = 512 (values) + 64 (queries).
// values out: interleaved pvT4: (b,g,v,j) at b*UU*VV + (g*VV+v)*4 + j.
// queries out: pqT[b][u][QQ]. Block 0 also zeroes denom[1024].
// ---------------------------------------------------------------------------
__global__ __launch_bounds__(256) void proj_kernel(const float* __restrict__ queries,
                                                   const float* __restrict__ values,
                                                   const float* __restrict__ w1,
                                                   const float* __restrict__ w2,
                                                   float* __restrict__ pqT,
                                                   float* __restrict__ pvT,
                                                   float* __restrict__ denom) {
    __shared__ float As[32][18];     // [k][row]
    __shared__ float Ws[32 * 128];   // [k][u]
    __shared__ float Ls[128][17];    // [u][row] epilogue transpose
    const int bid = blockIdx.x;
    const int tid = threadIdx.x;
    if (bid == 0) *(float4*)&denom[tid * 4] = make_float4(0.f, 0.f, 0.f, 0.f);

    const bool isv = (bid < 512);
    const float* A; const float* W; int b, r0;
    if (isv) {                             // values: 8192 rows
        b = bid >> 7; r0 = (bid & 127) * 16;
        A = values + ((size_t)(b * VV + r0)) * HH;  W = w2;
    } else {                               // queries: 1024 rows
        const int q = bid - 512;
        b = q >> 4; r0 = (q & 15) * 16;
        A = queries + ((size_t)(b * QQ + r0)) * HH; W = w1;
    }

    const int tx = tid & 31;         // u-group: u = tx*4 .. tx*4+3
    const int ty = tid >> 5;         // row-pair: rows 2ty, 2ty+1
    float4 acc0 = make_float4(0.f, 0.f, 0.f, 0.f);
    float4 acc1 = make_float4(0.f, 0.f, 0.f, 0.f);

    for (int k0 = 0; k0 < HH; k0 += 32) {
        if (tid < 128) {             // A tile: 16 rows x 32 k, store transposed
            const int r = tid >> 3, kk4 = (tid & 7) * 4;
            const float4 a = *(const float4*)&A[(size_t)r * HH + k0 + kk4];
            As[kk4 + 0][r] = a.x; As[kk4 + 1][r] = a.y;
            As[kk4 + 2][r] = a.z; As[kk4 + 3][r] = a.w;
        }
#pragma unroll
        for (int t = 0; t < 4; t++) {  // W tile: 32 k x 128 u
            const int f = tid + t * 256;
            const int kk = f >> 5, u4 = (f & 31) * 4;
            *(float4*)&Ws[kk * 128 + u4] = *(const float4*)&W[(size_t)(k0 + kk) * UU + u4];
        }
        __syncthreads();
#pragma unroll
        for (int kk = 0; kk < 32; kk++) {
            const float2 a = *(const float2*)&As[kk][ty * 2];   // broadcast
            const float4 w = *(const float4*)&Ws[kk * 128 + tx * 4];
            fma4(acc0, a.x, w);
            fma4(acc1, a.y, w);
        }
        __syncthreads();
    }
    {
        const float a0[4] = {acc0.x, acc0.y, acc0.z, acc0.w};
        const float a1[4] = {acc1.x, acc1.y, acc1.z, acc1.w};
#pragma unroll
        for (int i = 0; i < 4; i++) {
            Ls[tx * 4 + i][ty * 2 + 0] = __builtin_amdgcn_exp2f(a0[i] * C2E);
            Ls[tx * 4 + i][ty * 2 + 1] = __builtin_amdgcn_exp2f(a1[i] * C2E);
        }
    }
    __syncthreads();
    if (isv) {
        float* Ob = pvT + (size_t)b * UU * VV;
#pragma unroll
        for (int t = 0; t < 2; t++) {
            const int idx = tid + t * 256;
            const int g = idx >> 4, r = idx & 15;
            float4 o;
            o.x = Ls[4 * g + 0][r]; o.y = Ls[4 * g + 1][r];
            o.z = Ls[4 * g + 2][r]; o.w = Ls[4 * g + 3][r];
            *(float4*)&Ob[((size_t)g * VV + r0 + r) * 4] = o;
        }
    } else {
        float* O = pqT + (size_t)b * UU * QQ + r0;
        const int uu = tid >> 1, half = (tid & 1) * 8;
        float4 o0, o1;
        o0.x = Ls[uu][half + 0]; o0.y = Ls[uu][half + 1];
        o0.z = Ls[uu][half + 2]; o0.w = Ls[uu][half + 3];
        o1.x = Ls[uu][half + 4]; o1.y = Ls[uu][half + 5];
        o1.z = Ls[uu][half + 6]; o1.w = Ls[uu][half + 7];
        float* dst = O + (size_t)uu * QQ + half;
        *(float4*)dst = o0;
        *(float4*)(dst + 4) = o1;
    }
}

// ---------------------------------------------------------------------------
// Fused scores+softmax-numerator+partial-out. grid = 4b*32qb*8vs = 1024,
// 512 threads (8 waves).
// Phase A (R7): exp-product form — e = Eq*Ev via one FMA (1+Eq*Ev); grouped
//   rcp over 4 u. Only 2 rcp per (4u,2q). u-range split across thread halves.
// Phase B (R6): (qh,vh) split across 4 half-waves — each reads 128 v rows
//   (values dup x2 = 1 MB/block; R7's all-256-v q-split was dup x4 = 2 MB ->
//   TEX-bound at VALUBusy 28%). LDS reduce over v-halves, plain slab stores.
// scratch[] aliases phase-A combine buf (8 KB) and phase-B reduce buf (16 KB).
// ---------------------------------------------------------------------------
__global__ __launch_bounds__(512, 8) void fused_kernel(const float* __restrict__ pqT,
                                                       const float* __restrict__ pvT,
                                                       const float* __restrict__ vvec,
                                                       const float* __restrict__ values,
                                                       float* __restrict__ slab,
                                                       float* __restrict__ denom) {
    __shared__ float att[256][8];      // [v][q] 8 KB, persists A->B
    __shared__ float scratch[8][512];  // 16 KB: A-combine (first 8 KB) / B-reduce
    __shared__ float wred[4][8];
    const int tid = threadIdx.x;
    const int bid = blockIdx.x;
    const int vs = bid & 7, qb = (bid >> 3) & 31, b = bid >> 8;
    const int qbase = qb * 8, vbase = vs * 256;

    // ---- Phase A ----
    const int vloc = tid & 255, uh = tid >> 8;      // uh wave-uniform
    const int v = vbase + vloc;

    float vsum = 0.0f;
#pragma unroll
    for (int u4 = 0; u4 < UU; u4 += 4) {
        const float4 t = *(const float4*)&vvec[u4];
        vsum += t.x + t.y + t.z + t.w;
    }

    const float* pv4p = pvT + (size_t)b * UU * VV + (size_t)v * 4;   // Ev
    const float* pqp  = pqT + (size_t)b * UU * QQ + qbase;           // Eq, uniform

    float2 acc[4];
#pragma unroll
    for (int p = 0; p < 4; p++) acc[p] = make_float2(0.f, 0.f);

    for (int g = 0; g < 16; g++) {
        const int G = uh * 16 + g;                  // global u-group
        const float4 ev = *(const float4*)&pv4p[(size_t)G * VV * 4];
        const float4 wq = *(const float4*)&vvec[G * 4];      // uniform
        const float w0 = 2.f * wq.x, w1 = 2.f * wq.y;
        const float w2 = 2.f * wq.z, w3 = 2.f * wq.w;
        const int u0 = G * 4;
#pragma unroll
        for (int p = 0; p < 4; p++) {
            const float2 qa  = *(const float2*)&pqp[(size_t)(u0 + 0) * QQ + 2 * p];
            const float2 qb2 = *(const float2*)&pqp[(size_t)(u0 + 1) * QQ + 2 * p];
            const float2 qc  = *(const float2*)&pqp[(size_t)(u0 + 2) * QQ + 2 * p];
            const float2 qd  = *(const float2*)&pqp[(size_t)(u0 + 3) * QQ + 2 * p];
            const float2 a1 = fmass(qa, ev.x, 1.0f);   // 1 + Eq*Ev
            const float2 b1 = fmass(qb2, ev.y, 1.0f);
            const float2 c1 = fmass(qc, ev.z, 1.0f);
            const float2 d1 = fmass(qd, ev.w, 1.0f);
            const float2 pab = mul2(a1, b1), pcd = mul2(c1, d1);
            const float2 nab = fmas(a1, w1, muls(b1, w0));   // w0*b1 + w1*a1
            const float2 ncd = fmas(c1, w3, muls(d1, w2));
            const float2 num = fma2(nab, pcd, mul2(ncd, pab));
            const float2 den = mul2(pab, pcd);
            acc[p] = fma2(num, rcp2(den), acc[p]);
        }
    }

    // combine u-halves: upper half -> LDS, lower half finishes
    float* cbuf = &scratch[0][0];
    if (uh == 1) {
#pragma unroll
        for (int p = 0; p < 4; p++)
            *(float2*)&cbuf[vloc * 8 + 2 * p] = acc[p];
    }
    __syncthreads();
    if (uh == 0) {
#pragma unroll
        for (int p = 0; p < 4; p++) {
            const float2 hi = *(const float2*)&cbuf[vloc * 8 + 2 * p];
            float2 e;
            e.x = __builtin_amdgcn_exp2f((vsum - (acc[p].x + hi.x)) * LOG2E);
            e.y = __builtin_amdgcn_exp2f((vsum - (acc[p].y + hi.y)) * LOG2E);
            att[vloc][2 * p + 0] = e.x;
            att[vloc][2 * p + 1] = e.y;
            acc[p] = e;
        }
#pragma unroll
        for (int off = 1; off < 64; off <<= 1) {
#pragma unroll
            for (int p = 0; p < 4; p++) {
                acc[p].x += __shfl_xor(acc[p].x, off, 64);
                acc[p].y += __shfl_xor(acc[p].y, off, 64);
            }
        }
        if ((tid & 63) == 0) {
            const int w = tid >> 6;   // 0..3
#pragma unroll
            for (int p = 0; p < 4; p++) {
                wred[w][2 * p + 0] = acc[p].x;
                wred[w][2 * p + 1] = acc[p].y;
            }
        }
    }
    __syncthreads();
    if (tid < 8)
        atomicAdd(&denom[b * QQ + qbase + tid],
                  wred[0][tid] + wred[1][tid] + wred[2][tid] + wred[3][tid]);

    // ---- Phase B: (qh, vh) split across the 4 half-waves (R6 structure) ----
    const int hg = tid & 127, sel = tid >> 7;       // sel wave-uniform
    const int qh = sel & 1, vh = sel >> 1;
    const int h0 = hg * 4;
    const float* vp = values + ((size_t)(b * VV + vbase + vh * 128)) * HH + h0;

    float4 oacc[4];
#pragma unroll
    for (int j = 0; j < 4; j++) oacc[j] = make_float4(0.f, 0.f, 0.f, 0.f);

#pragma unroll 2
    for (int vv = 0; vv < 128; vv++) {
        const float4 w = *(const float4*)&vp[(size_t)vv * HH];
        const float4 a = *(const float4*)&att[vh * 128 + vv][qh * 4];  // broadcast b128
        fma4(oacc[0], a.x, w); fma4(oacc[1], a.y, w);
        fma4(oacc[2], a.z, w); fma4(oacc[3], a.w, w);
    }

    if (vh == 1) {
#pragma unroll
        for (int j = 0; j < 4; j++) *(float4*)&scratch[qh * 4 + j][h0] = oacc[j];
    }
    __syncthreads();
    if (vh == 0) {
        float* sp = slab + (size_t)vs * (BB * QQ * HH);
#pragma unroll
        for (int j = 0; j < 4; j++) {
            const float4 p4 = *(const float4*)&scratch[qh * 4 + j][h0];
            const int q = qh * 4 + j;
            float4 o;
            o.x = oacc[j].x + p4.x; o.y = oacc[j].y + p4.y;
            o.z = oacc[j].z + p4.z; o.w = oacc[j].w + p4.w;
            *(float4*)&sp[((size_t)(b * QQ + qbase + q)) * HH + h0] = o;
        }
    }
}

// ---------------------------------------------------------------------------
// out = (sum of 8 slabs) * rcp(denom[row]). 131072 float4s, grid 512.
// ---------------------------------------------------------------------------
__global__ __launch_bounds__(256) void reduce_kernel(const float* __restrict__ slab,
                                                     const float* __restrict__ denom,
                                                     float* __restrict__ out) {
    const int i = blockIdx.x * 256 + threadIdx.x;    // float4 index
    const float r = __builtin_amdgcn_rcpf(denom[i >> 7]);
    const float4* s4 = (const float4*)slab;
    float4 s = s4[i];
#pragma unroll
    for (int k = 1; k < 8; k++) {
        const float4 p = s4[(size_t)k * (BB * QQ * HH / 4) + i];
        s.x += p.x; s.y += p.y; s.z += p.z; s.w += p.w;
    }
    s.x *= r; s.y *= r; s.z *= r; s.w *= r;
    ((float4*)out)[i] = s;
}

// ---------------------------------------------------------------------------
extern "C" void kernel_launch(void* const* d_in, const int* in_sizes, int n_in,
                              void* d_out, int out_size, void* d_ws, size_t ws_size,
                              hipStream_t stream) {
    const float* queries = (const float*)d_in[0];  // [B,Q,H]
    const float* values  = (const float*)d_in[1];  // [B,V,H]
    const float* w1      = (const float*)d_in[2];  // [H,U]
    const float* w2      = (const float*)d_in[3];  // [H,U]
    const float* vvec    = (const float*)d_in[4];  // [U]
    float* out = (float*)d_out;

    // ws (floats): pqT[131072] | pvT[1048576] | denom[1024] | slab[8*524288]
    float* ws    = (float*)d_ws;
    float* pqT   = ws;
    float* pvT   = pqT + BB * UU * QQ;
    float* denom = pvT + (size_t)BB * UU * VV;
    float* slab  = denom + BB * QQ;

    proj_kernel<<<512 + 64, 256, 0, stream>>>(queries, values, w1, w2, pqT, pvT, denom);
    fused_kernel<<<BB * (QQ / 8) * (VV / 256), 512, 0, stream>>>(pqT, pvT, vvec, values, slab, denom);
    reduce_kernel<<<(BB * QQ * HH) / 4 / 256, 256, 0, stream>>>(slab, denom, out);
}

// Round 9
// 189.525 us; speedup vs baseline: 1.2689x; 1.1473x over previous
//
#include <hip/hip_runtime.h>

#define BB 4
#define QQ 256
#define VV 2048
#define HH 512
#define UU 128

// tanh arg scale folded into projections: C2E = 2*log2(e); exp(x)=exp2(x*LOG2E)
#define C2E   2.8853900817779268f
#define LOG2E 1.4426950408889634f

__device__ __forceinline__ void fma4(float4& a, float s, const float4& w) {
    a.x = fmaf(s, w.x, a.x);
    a.y = fmaf(s, w.y, a.y);
    a.z = fmaf(s, w.z, a.z);
    a.w = fmaf(s, w.w, a.w);
}
__device__ __forceinline__ float2 rcp2(float2 x) {
    return make_float2(__builtin_amdgcn_rcpf(x.x), __builtin_amdgcn_rcpf(x.y));
}
__device__ __forceinline__ float2 mul2(float2 a, float2 b) { return make_float2(a.x*b.x, a.y*b.y); }
__device__ __forceinline__ float2 muls(float2 a, float s)  { return make_float2(a.x*s, a.y*s); }
__device__ __forceinline__ float2 fma2(float2 a, float2 b, float2 c) {
    return make_float2(fmaf(a.x, b.x, c.x), fmaf(a.y, b.y, c.y));
}
__device__ __forceinline__ float2 fmas(float2 a, float s, float2 c) {
    return make_float2(fmaf(a.x, s, c.x), fmaf(a.y, s, c.y));
}

// ---------------------------------------------------------------------------
// Projection GEMM -> EXPONENTIATED, INTERLEAVED transposed output:
//   E[(g,r,j)] = exp2( C2E * sum_h A[r][h]*W[h][4g+j] )   stored at
//   base + (g*ROWS + r)*4 + j    (g = u>>2, j = u&3)
// so fused reads a 4-u group as ONE float4 (pv) and an 8q x 4u Eq block as
// 8 contiguous float4s (pq). 16 rows x 128 u per block, BK=32.
// grid = 512 (values, ROWS=VV) + 64 (queries, ROWS=QQ). Block 0 zeroes denom.
// ---------------------------------------------------------------------------
__global__ __launch_bounds__(256) void proj_kernel(const float* __restrict__ queries,
                                                   const float* __restrict__ values,
                                                   const float* __restrict__ w1,
                                                   const float* __restrict__ w2,
                                                   float* __restrict__ pqI,
                                                   float* __restrict__ pvI,
                                                   float* __restrict__ denom) {
    __shared__ float As[32][18];     // [k][row]
    __shared__ float Ws[32 * 128];   // [k][u]
    __shared__ float Ls[128][17];    // [u][row] epilogue transpose
    const int bid = blockIdx.x;
    const int tid = threadIdx.x;
    if (bid == 0) *(float4*)&denom[tid * 4] = make_float4(0.f, 0.f, 0.f, 0.f);

    const bool isv = (bid < 512);
    const float* A; const float* W; int b, r0, ROWS; float* Ob;
    if (isv) {                             // values: 8192 rows
        b = bid >> 7; r0 = (bid & 127) * 16;
        A = values + ((size_t)(b * VV + r0)) * HH;  W = w2;
        Ob = pvI + (size_t)b * UU * VV;  ROWS = VV;
    } else {                               // queries: 1024 rows
        const int q = bid - 512;
        b = q >> 4; r0 = (q & 15) * 16;
        A = queries + ((size_t)(b * QQ + r0)) * HH; W = w1;
        Ob = pqI + (size_t)b * UU * QQ;  ROWS = QQ;
    }

    const int tx = tid & 31;         // u-group: u = tx*4 .. tx*4+3
    const int ty = tid >> 5;         // row-pair: rows 2ty, 2ty+1
    float4 acc0 = make_float4(0.f, 0.f, 0.f, 0.f);
    float4 acc1 = make_float4(0.f, 0.f, 0.f, 0.f);

    for (int k0 = 0; k0 < HH; k0 += 32) {
        if (tid < 128) {             // A tile: 16 rows x 32 k, store transposed
            const int r = tid >> 3, kk4 = (tid & 7) * 4;
            const float4 a = *(const float4*)&A[(size_t)r * HH + k0 + kk4];
            As[kk4 + 0][r] = a.x; As[kk4 + 1][r] = a.y;
            As[kk4 + 2][r] = a.z; As[kk4 + 3][r] = a.w;
        }
#pragma unroll
        for (int t = 0; t < 4; t++) {  // W tile: 32 k x 128 u
            const int f = tid + t * 256;
            const int kk = f >> 5, u4 = (f & 31) * 4;
            *(float4*)&Ws[kk * 128 + u4] = *(const float4*)&W[(size_t)(k0 + kk) * UU + u4];
        }
        __syncthreads();
#pragma unroll
        for (int kk = 0; kk < 32; kk++) {
            const float2 a = *(const float2*)&As[kk][ty * 2];   // broadcast
            const float4 w = *(const float4*)&Ws[kk * 128 + tx * 4];
            fma4(acc0, a.x, w);
            fma4(acc1, a.y, w);
        }
        __syncthreads();
    }
    {
        const float a0[4] = {acc0.x, acc0.y, acc0.z, acc0.w};
        const float a1[4] = {acc1.x, acc1.y, acc1.z, acc1.w};
#pragma unroll
        for (int i = 0; i < 4; i++) {
            Ls[tx * 4 + i][ty * 2 + 0] = __builtin_amdgcn_exp2f(a0[i] * C2E);
            Ls[tx * 4 + i][ty * 2 + 1] = __builtin_amdgcn_exp2f(a1[i] * C2E);
        }
    }
    __syncthreads();
#pragma unroll
    for (int t = 0; t < 2; t++) {    // 512 float4 chunks: (g = idx>>4, r = idx&15)
        const int idx = tid + t * 256;
        const int g = idx >> 4, r = idx & 15;
        float4 o;
        o.x = Ls[4 * g + 0][r]; o.y = Ls[4 * g + 1][r];
        o.z = Ls[4 * g + 2][r]; o.w = Ls[4 * g + 3][r];
        *(float4*)&Ob[((size_t)g * ROWS + r0 + r) * 4] = o;
    }
}

// ---------------------------------------------------------------------------
// Fused scores+softmax-numerator+partial-out. grid = 4b*32qb*8vs = 1024,
// 512 threads (8 waves), __launch_bounds__(512, 6): R8's (512,8) capped VGPRs
// at 64 (compiler hit 32) -> load serialization, VALUBusy 33%. 6 waves/EU
// allows ~85 VGPRs, 3 blocks/CU (75% occ), loads stay in flight.
// Phase A: exp-product form (e = Eq*Ev, 1+e as one FMA; grouped rcp over 4 u,
//   2 rcp per (4u,2q)); u-range split across thread halves; per g-iter only
//   9 VMEM loads (8 float4 Eq from interleaved pqI + 1 float4 Ev), ev
//   prefetched one iteration ahead.
// Phase B: (qh,vh) split across 4 half-waves (R6 structure, values dup x2).
// ---------------------------------------------------------------------------
__global__ __launch_bounds__(512, 6) void fused_kernel(const float* __restrict__ pqI,
                                                       const float* __restrict__ pvI,
                                                       const float* __restrict__ vvec,
                                                       const float* __restrict__ values,
                                                       float* __restrict__ slab,
                                                       float* __restrict__ denom) {
    __shared__ float att[256][8];      // [v][q] 8 KB, persists A->B
    __shared__ float scratch[8][512];  // 16 KB: A-combine (first 8 KB) / B-reduce
    __shared__ float wred[4][8];
    const int tid = threadIdx.x;
    const int bid = blockIdx.x;
    const int vs = bid & 7, qb = (bid >> 3) & 31, b = bid >> 8;
    const int qbase = qb * 8, vbase = vs * 256;

    // ---- Phase A ----
    const int vloc = tid & 255, uh = tid >> 8;      // uh wave-uniform
    const int v = vbase + vloc;

    float vsum = 0.0f;
#pragma unroll
    for (int u4 = 0; u4 < UU; u4 += 4) {
        const float4 t = *(const float4*)&vvec[u4];
        vsum += t.x + t.y + t.z + t.w;
    }

    const float* pv4 = pvI + (size_t)b * UU * VV + (size_t)v * 4;      // Ev
    const float* pq4 = pqI + (size_t)b * UU * QQ + (size_t)qbase * 4;  // Eq blocks

    float2 acc[4];
#pragma unroll
    for (int p = 0; p < 4; p++) acc[p] = make_float2(0.f, 0.f);

    const int G0 = uh * 16;
    float4 ev = *(const float4*)&pv4[(size_t)G0 * VV * 4];   // prefetch g=0

    for (int g = 0; g < 16; g++) {
        const int G = G0 + g;
        // Eq block for this g: 8 contiguous float4s (all-lane-uniform address)
        const float* eqp = &pq4[(size_t)G * QQ * 4];
        float4 eq[8];
#pragma unroll
        for (int qi = 0; qi < 8; qi++) eq[qi] = *(const float4*)&eqp[qi * 4];
        // prefetch next ev while this iteration computes
        float4 evn;
        if (g < 15) evn = *(const float4*)&pv4[(size_t)(G + 1) * VV * 4];
        const float4 wq = *(const float4*)&vvec[G * 4];
        const float w0 = 2.f * wq.x, w1 = 2.f * wq.y;
        const float w2 = 2.f * wq.z, w3 = 2.f * wq.w;
#pragma unroll
        for (int p = 0; p < 4; p++) {
            const float4 e0 = eq[2 * p], e1 = eq[2 * p + 1];
            const float2 a1 = make_float2(fmaf(e0.x, ev.x, 1.f), fmaf(e1.x, ev.x, 1.f));
            const float2 b1 = make_float2(fmaf(e0.y, ev.y, 1.f), fmaf(e1.y, ev.y, 1.f));
            const float2 c1 = make_float2(fmaf(e0.z, ev.z, 1.f), fmaf(e1.z, ev.z, 1.f));
            const float2 d1 = make_float2(fmaf(e0.w, ev.w, 1.f), fmaf(e1.w, ev.w, 1.f));
            const float2 pab = mul2(a1, b1), pcd = mul2(c1, d1);
            const float2 nab = fmas(a1, w1, muls(b1, w0));   // w0*b1 + w1*a1
            const float2 ncd = fmas(c1, w3, muls(d1, w2));
            const float2 num = fma2(nab, pcd, mul2(ncd, pab));
            const float2 den = mul2(pab, pcd);
            acc[p] = fma2(num, rcp2(den), acc[p]);
        }
        ev = evn;
    }

    // combine u-halves: upper half -> LDS, lower half finishes
    float* cbuf = &scratch[0][0];
    if (uh == 1) {
#pragma unroll
        for (int p = 0; p < 4; p++)
            *(float2*)&cbuf[vloc * 8 + 2 * p] = acc[p];
    }
    __syncthreads();
    if (uh == 0) {
#pragma unroll
        for (int p = 0; p < 4; p++) {
            const float2 hi = *(const float2*)&cbuf[vloc * 8 + 2 * p];
            float2 e;
            e.x = __builtin_amdgcn_exp2f((vsum - (acc[p].x + hi.x)) * LOG2E);
            e.y = __builtin_amdgcn_exp2f((vsum - (acc[p].y + hi.y)) * LOG2E);
            att[vloc][2 * p + 0] = e.x;
            att[vloc][2 * p + 1] = e.y;
            acc[p] = e;
        }
#pragma unroll
        for (int off = 1; off < 64; off <<= 1) {
#pragma unroll
            for (int p = 0; p < 4; p++) {
                acc[p].x += __shfl_xor(acc[p].x, off, 64);
                acc[p].y += __shfl_xor(acc[p].y, off, 64);
            }
        }
        if ((tid & 63) == 0) {
            const int w = tid >> 6;   // 0..3
#pragma unroll
            for (int p = 0; p < 4; p++) {
                wred[w][2 * p + 0] = acc[p].x;
                wred[w][2 * p + 1] = acc[p].y;
            }
        }
    }
    __syncthreads();
    if (tid < 8)
        atomicAdd(&denom[b * QQ + qbase + tid],
                  wred[0][tid] + wred[1][tid] + wred[2][tid] + wred[3][tid]);

    // ---- Phase B: (qh, vh) split across the 4 half-waves (R6 structure) ----
    const int hg = tid & 127, sel = tid >> 7;       // sel wave-uniform
    const int qh = sel & 1, vh = sel >> 1;
    const int h0 = hg * 4;
    const float* vp = values + ((size_t)(b * VV + vbase + vh * 128)) * HH + h0;

    float4 oacc[4];
#pragma unroll
    for (int j = 0; j < 4; j++) oacc[j] = make_float4(0.f, 0.f, 0.f, 0.f);

#pragma unroll 2
    for (int vv = 0; vv < 128; vv++) {
        const float4 w = *(const float4*)&vp[(size_t)vv * HH];
        const float4 a = *(const float4*)&att[vh * 128 + vv][qh * 4];  // broadcast b128
        fma4(oacc[0], a.x, w); fma4(oacc[1], a.y, w);
        fma4(oacc[2], a.z, w); fma4(oacc[3], a.w, w);
    }

    if (vh == 1) {
#pragma unroll
        for (int j = 0; j < 4; j++) *(float4*)&scratch[qh * 4 + j][h0] = oacc[j];
    }
    __syncthreads();
    if (vh == 0) {
        float* sp = slab + (size_t)vs * (BB * QQ * HH);
#pragma unroll
        for (int j = 0; j < 4; j++) {
            const float4 p4 = *(const float4*)&scratch[qh * 4 + j][h0];
            const int q = qh * 4 + j;
            float4 o;
            o.x = oacc[j].x + p4.x; o.y = oacc[j].y + p4.y;
            o.z = oacc[j].z + p4.z; o.w = oacc[j].w + p4.w;
            *(float4*)&sp[((size_t)(b * QQ + qbase + q)) * HH + h0] = o;
        }
    }
}

// ---------------------------------------------------------------------------
// out = (sum of 8 slabs) * rcp(denom[row]). 131072 float4s, grid 512.
// ---------------------------------------------------------------------------
__global__ __launch_bounds__(256) void reduce_kernel(const float* __restrict__ slab,
                                                     const float* __restrict__ denom,
                                                     float* __restrict__ out) {
    const int i = blockIdx.x * 256 + threadIdx.x;    // float4 index
    const float r = __builtin_amdgcn_rcpf(denom[i >> 7]);
    const float4* s4 = (const float4*)slab;
    float4 s = s4[i];
#pragma unroll
    for (int k = 1; k < 8; k++) {
        const float4 p = s4[(size_t)k * (BB * QQ * HH / 4) + i];
        s.x += p.x; s.y += p.y; s.z += p.z; s.w += p.w;
    }
    s.x *= r; s.y *= r; s.z *= r; s.w *= r;
    ((float4*)out)[i] = s;
}

// ---------------------------------------------------------------------------
extern "C" void kernel_launch(void* const* d_in, const int* in_sizes, int n_in,
                              void* d_out, int out_size, void* d_ws, size_t ws_size,
                              hipStream_t stream) {
    const float* queries = (const float*)d_in[0];  // [B,Q,H]
    const float* values  = (const float*)d_in[1];  // [B,V,H]
    const float* w1      = (const float*)d_in[2];  // [H,U]
    const float* w2      = (const float*)d_in[3];  // [H,U]
    const float* vvec    = (const float*)d_in[4];  // [U]
    float* out = (float*)d_out;

    // ws (floats): pqI[131072] | pvI[1048576] | denom[1024] | slab[8*524288]
    float* ws    = (float*)d_ws;
    float* pqI   = ws;
    float* pvI   = pqI + BB * UU * QQ;
    float* denom = pvI + (size_t)BB * UU * VV;
    float* slab  = denom + BB * QQ;

    proj_kernel<<<512 + 64, 256, 0, stream>>>(queries, values, w1, w2, pqI, pvI, denom);
    fused_kernel<<<BB * (QQ / 8) * (VV / 256), 512, 0, stream>>>(pqI, pvI, vvec, values, slab, denom);
    reduce_kernel<<<(BB * QQ * HH) / 4 / 256, 256, 0, stream>>>(slab, denom, out);
}

// Round 10
// 173.347 us; speedup vs baseline: 1.3874x; 1.0933x over previous
//
#include <hip/hip_runtime.h>

#define BB 4
#define QQ 256
#define VV 2048
#define HH 512
#define UU 128

// tanh arg scale folded into projections: C2E = 2*log2(e); exp(x)=exp2(x*LOG2E)
#define C2E   2.8853900817779268f
#define LOG2E 1.4426950408889634f

__device__ __forceinline__ void fma4(float4& a, float s, const float4& w) {
    a.x = fmaf(s, w.x, a.x);
    a.y = fmaf(s, w.y, a.y);
    a.z = fmaf(s, w.z, a.z);
    a.w = fmaf(s, w.w, a.w);
}
__device__ __forceinline__ float2 rcp2(float2 x) {
    return make_float2(__builtin_amdgcn_rcpf(x.x), __builtin_amdgcn_rcpf(x.y));
}
__device__ __forceinline__ float2 mul2(float2 a, float2 b) { return make_float2(a.x*b.x, a.y*b.y); }
__device__ __forceinline__ float2 muls(float2 a, float s)  { return make_float2(a.x*s, a.y*s); }
__device__ __forceinline__ float2 fma2(float2 a, float2 b, float2 c) {
    return make_float2(fmaf(a.x, b.x, c.x), fmaf(a.y, b.y, c.y));
}
__device__ __forceinline__ float2 fmas(float2 a, float s, float2 c) {
    return make_float2(fmaf(a.x, s, c.x), fmaf(a.y, s, c.y));
}

// ---------------------------------------------------------------------------
// Projection GEMM -> EXPONENTIATED, INTERLEAVED transposed output:
//   E[(g,r,j)] = exp2( C2E * sum_h A[r][h]*W[h][4g+j] ),  at (g*ROWS+r)*4+j.
// R10: 32 rows x 128 u per block, 4 rows/thread (R9's 2 rows/thread made the
// kernel W-LDS-pipe-bound ~25 us: each 1KB Ws read fed only 8 FMAs; now 16).
// grid = 256 (values) + 32 (queries) = 288. Ls epilogue aliases As+Ws.
// Block 0 zeroes denom.
// ---------------------------------------------------------------------------
__global__ __launch_bounds__(256) void proj_kernel(const float* __restrict__ queries,
                                                   const float* __restrict__ values,
                                                   const float* __restrict__ w1,
                                                   const float* __restrict__ w2,
                                                   float* __restrict__ pqI,
                                                   float* __restrict__ pvI,
                                                   float* __restrict__ denom) {
    __shared__ float smem[32 * 36 + 32 * 128];   // As[32][36] | Ws[32*128]; Ls aliases
    float (*As)[36] = (float(*)[36])smem;        // [k][row], stride 36 (16B-aligned rows)
    float* Ws = smem + 32 * 36;                  // [k][u]
    float (*Ls)[36] = (float(*)[36])smem;        // [u][row], epilogue (after barrier)

    const int bid = blockIdx.x;
    const int tid = threadIdx.x;
    if (bid == 0) *(float4*)&denom[tid * 4] = make_float4(0.f, 0.f, 0.f, 0.f);

    const bool isv = (bid < 256);
    const float* A; const float* W; int b, r0, ROWS; float* Ob;
    if (isv) {                             // values: 8192 rows, 64 blocks/batch
        b = bid >> 6; r0 = (bid & 63) * 32;
        A = values + ((size_t)(b * VV + r0)) * HH;  W = w2;
        Ob = pvI + (size_t)b * UU * VV;  ROWS = VV;
    } else {                               // queries: 1024 rows, 8 blocks/batch
        const int q = bid - 256;
        b = q >> 3; r0 = (q & 7) * 32;
        A = queries + ((size_t)(b * QQ + r0)) * HH; W = w1;
        Ob = pqI + (size_t)b * UU * QQ;  ROWS = QQ;
    }

    const int tx = tid & 31;         // u-group: u = tx*4 .. tx*4+3
    const int ty = tid >> 5;         // row-quad: rows 4ty .. 4ty+3
    float4 acc[4];
#pragma unroll
    for (int j = 0; j < 4; j++) acc[j] = make_float4(0.f, 0.f, 0.f, 0.f);

    for (int k0 = 0; k0 < HH; k0 += 32) {
        {   // A tile: 32 rows x 32 k, transposed store; one float4 per thread
            const int r = tid >> 3, kk4 = (tid & 7) * 4;
            const float4 a = *(const float4*)&A[(size_t)r * HH + k0 + kk4];
            As[kk4 + 0][r] = a.x; As[kk4 + 1][r] = a.y;
            As[kk4 + 2][r] = a.z; As[kk4 + 3][r] = a.w;
        }
#pragma unroll
        for (int t = 0; t < 4; t++) {  // W tile: 32 k x 128 u
            const int f = tid + t * 256;
            const int kk = f >> 5, u4 = (f & 31) * 4;
            *(float4*)&Ws[kk * 128 + u4] = *(const float4*)&W[(size_t)(k0 + kk) * UU + u4];
        }
        __syncthreads();
#pragma unroll
        for (int kk = 0; kk < 32; kk++) {
            const float4 a = *(const float4*)&As[kk][ty * 4];       // 4 rows
            const float4 w = *(const float4*)&Ws[kk * 128 + tx * 4];
            fma4(acc[0], a.x, w);
            fma4(acc[1], a.y, w);
            fma4(acc[2], a.z, w);
            fma4(acc[3], a.w, w);
        }
        __syncthreads();
    }
    // epilogue: exp2 + transpose via Ls (aliases As/Ws — barrier passed above)
#pragma unroll
    for (int j = 0; j < 4; j++) {
        const float aa[4] = {acc[j].x, acc[j].y, acc[j].z, acc[j].w};
#pragma unroll
        for (int i = 0; i < 4; i++)
            Ls[tx * 4 + i][ty * 4 + j] = __builtin_amdgcn_exp2f(aa[i] * C2E);
    }
    __syncthreads();
#pragma unroll
    for (int t = 0; t < 4; t++) {    // 1024 float4 chunks: (g = idx>>5, r = idx&31)
        const int idx = tid + t * 256;
        const int g = idx >> 5, r = idx & 31;
        float4 o;
        o.x = Ls[4 * g + 0][r]; o.y = Ls[4 * g + 1][r];
        o.z = Ls[4 * g + 2][r]; o.w = Ls[4 * g + 3][r];
        *(float4*)&Ob[((size_t)g * ROWS + r0 + r) * 4] = o;
    }
}

// ---------------------------------------------------------------------------
// Fused scores+softmax-numerator+partial-out. grid = 4b*16qb*8vs = 512,
// 512 threads (8 waves), launch_bounds(512,6).
// qtile=16 (R9 was 8): each values row now serves 16 q -> phase-B L1 traffic
// halves (1 GB -> 0.5 GB), the dominant fused floor.
// Phase A: exp-product grouped-rcp (2 rcp per (4u, 2q)); u-split across
//   thread halves; eq loads inside p-loop (small live ranges).
// Phase B: (qh: 8 q, vh: 128 v) split across 4 half-waves; LDS reduce over
//   v-halves; plain stores to private slab[vs].
// vs stays in bid low 3 bits: the 16 qb-blocks sharing a values slice share
// bid%8 (same XCD L2) — keep.
// ---------------------------------------------------------------------------
__global__ __launch_bounds__(512, 6) void fused_kernel(const float* __restrict__ pqI,
                                                       const float* __restrict__ pvI,
                                                       const float* __restrict__ vvec,
                                                       const float* __restrict__ values,
                                                       float* __restrict__ slab,
                                                       float* __restrict__ denom) {
    __shared__ float att[256][16];      // [v][q] 16 KB, persists A->B
    __shared__ float scratch[16][512];  // 32 KB: A-combine (first 16 KB) / B-reduce
    __shared__ float wred[4][16];
    const int tid = threadIdx.x;
    const int bid = blockIdx.x;
    const int vs = bid & 7, qb = (bid >> 3) & 15, b = bid >> 7;
    const int qbase = qb * 16, vbase = vs * 256;

    // ---- Phase A ----
    const int vloc = tid & 255, uh = tid >> 8;      // uh wave-uniform
    const int v = vbase + vloc;

    float vsum = 0.0f;
#pragma unroll
    for (int u4 = 0; u4 < UU; u4 += 4) {
        const float4 t = *(const float4*)&vvec[u4];
        vsum += t.x + t.y + t.z + t.w;
    }

    const float* pv4 = pvI + (size_t)b * UU * VV + (size_t)v * 4;      // Ev
    const float* pq4 = pqI + (size_t)b * UU * QQ + (size_t)qbase * 4;  // Eq blocks

    float2 acc[8];
#pragma unroll
    for (int p = 0; p < 8; p++) acc[p] = make_float2(0.f, 0.f);

    const int G0 = uh * 16;
    float4 ev = *(const float4*)&pv4[(size_t)G0 * VV * 4];   // prefetch g=0

    for (int g = 0; g < 16; g++) {
        const int G = G0 + g;
        const float* eqp = &pq4[(size_t)G * QQ * 4];  // 16q x 4u block, contiguous
        float4 evn;
        if (g < 15) evn = *(const float4*)&pv4[(size_t)(G + 1) * VV * 4];
        const float4 wq = *(const float4*)&vvec[G * 4];
        const float w0 = 2.f * wq.x, w1 = 2.f * wq.y;
        const float w2 = 2.f * wq.z, w3 = 2.f * wq.w;
#pragma unroll
        for (int p = 0; p < 8; p++) {
            const float4 e0 = *(const float4*)&eqp[(2 * p) * 4];      // q=2p
            const float4 e1 = *(const float4*)&eqp[(2 * p + 1) * 4];  // q=2p+1
            const float2 a1 = make_float2(fmaf(e0.x, ev.x, 1.f), fmaf(e1.x, ev.x, 1.f));
            const float2 b1 = make_float2(fmaf(e0.y, ev.y, 1.f), fmaf(e1.y, ev.y, 1.f));
            const float2 c1 = make_float2(fmaf(e0.z, ev.z, 1.f), fmaf(e1.z, ev.z, 1.f));
            const float2 d1 = make_float2(fmaf(e0.w, ev.w, 1.f), fmaf(e1.w, ev.w, 1.f));
            const float2 pab = mul2(a1, b1), pcd = mul2(c1, d1);
            const float2 nab = fmas(a1, w1, muls(b1, w0));   // w0*b1 + w1*a1
            const float2 ncd = fmas(c1, w3, muls(d1, w2));
            const float2 num = fma2(nab, pcd, mul2(ncd, pab));
            const float2 den = mul2(pab, pcd);
            acc[p] = fma2(num, rcp2(den), acc[p]);
        }
        ev = evn;
    }

    // combine u-halves: upper half -> LDS, lower half finishes
    float* cbuf = &scratch[0][0];
    if (uh == 1) {
#pragma unroll
        for (int p = 0; p < 8; p++)
            *(float2*)&cbuf[vloc * 16 + 2 * p] = acc[p];
    }
    __syncthreads();
    if (uh == 0) {
#pragma unroll
        for (int p = 0; p < 8; p++) {
            const float2 hi = *(const float2*)&cbuf[vloc * 16 + 2 * p];
            float2 e;
            e.x = __builtin_amdgcn_exp2f((vsum - (acc[p].x + hi.x)) * LOG2E);
            e.y = __builtin_amdgcn_exp2f((vsum - (acc[p].y + hi.y)) * LOG2E);
            att[vloc][2 * p + 0] = e.x;
            att[vloc][2 * p + 1] = e.y;
            acc[p] = e;
        }
#pragma unroll
        for (int off = 1; off < 64; off <<= 1) {
#pragma unroll
            for (int p = 0; p < 8; p++) {
                acc[p].x += __shfl_xor(acc[p].x, off, 64);
                acc[p].y += __shfl_xor(acc[p].y, off, 64);
            }
        }
        if ((tid & 63) == 0) {
            const int w = tid >> 6;   // 0..3
#pragma unroll
            for (int p = 0; p < 8; p++) {
                wred[w][2 * p + 0] = acc[p].x;
                wred[w][2 * p + 1] = acc[p].y;
            }
        }
    }
    __syncthreads();
    if (tid < 16)
        atomicAdd(&denom[b * QQ + qbase + tid],
                  wred[0][tid] + wred[1][tid] + wred[2][tid] + wred[3][tid]);

    // ---- Phase B: (qh: 8 q, vh: 128 v) split across the 4 half-waves ----
    const int hg = tid & 127, sel = tid >> 7;       // sel wave-uniform
    const int qh = sel & 1, vh = sel >> 1;
    const int h0 = hg * 4;
    const float* vp = values + ((size_t)(b * VV + vbase + vh * 128)) * HH + h0;

    float4 oacc[8];
#pragma unroll
    for (int j = 0; j < 8; j++) oacc[j] = make_float4(0.f, 0.f, 0.f, 0.f);

#pragma unroll 2
    for (int vv = 0; vv < 128; vv++) {
        const float4 w = *(const float4*)&vp[(size_t)vv * HH];
        const float4 a0 = *(const float4*)&att[vh * 128 + vv][qh * 8 + 0];  // broadcast
        const float4 a1 = *(const float4*)&att[vh * 128 + vv][qh * 8 + 4];
        fma4(oacc[0], a0.x, w); fma4(oacc[1], a0.y, w);
        fma4(oacc[2], a0.z, w); fma4(oacc[3], a0.w, w);
        fma4(oacc[4], a1.x, w); fma4(oacc[5], a1.y, w);
        fma4(oacc[6], a1.z, w); fma4(oacc[7], a1.w, w);
    }

    if (vh == 1) {
#pragma unroll
        for (int j = 0; j < 8; j++) *(float4*)&scratch[qh * 8 + j][h0] = oacc[j];
    }
    __syncthreads();
    if (vh == 0) {
        float* sp = slab + (size_t)vs * (BB * QQ * HH);
#pragma unroll
        for (int j = 0; j < 8; j++) {
            const float4 p4 = *(const float4*)&scratch[qh * 8 + j][h0];
            const int q = qh * 8 + j;
            float4 o;
            o.x = oacc[j].x + p4.x; o.y = oacc[j].y + p4.y;
            o.z = oacc[j].z + p4.z; o.w = oacc[j].w + p4.w;
            *(float4*)&sp[((size_t)(b * QQ + qbase + q)) * HH + h0] = o;
        }
    }
}

// ---------------------------------------------------------------------------
// out = (sum of 8 slabs) * rcp(denom[row]). 131072 float4s, grid 512.
// ---------------------------------------------------------------------------
__global__ __launch_bounds__(256) void reduce_kernel(const float* __restrict__ slab,
                                                     const float* __restrict__ denom,
                                                     float* __restrict__ out) {
    const int i = blockIdx.x * 256 + threadIdx.x;    // float4 index
    const float r = __builtin_amdgcn_rcpf(denom[i >> 7]);
    const float4* s4 = (const float4*)slab;
    float4 s = s4[i];
#pragma unroll
    for (int k = 1; k < 8; k++) {
        const float4 p = s4[(size_t)k * (BB * QQ * HH / 4) + i];
        s.x += p.x; s.y += p.y; s.z += p.z; s.w += p.w;
    }
    s.x *= r; s.y *= r; s.z *= r; s.w *= r;
    ((float4*)out)[i] = s;
}

// ---------------------------------------------------------------------------
extern "C" void kernel_launch(void* const* d_in, const int* in_sizes, int n_in,
                              void* d_out, int out_size, void* d_ws, size_t ws_size,
                              hipStream_t stream) {
    const float* queries = (const float*)d_in[0];  // [B,Q,H]
    const float* values  = (const float*)d_in[1];  // [B,V,H]
    const float* w1      = (const float*)d_in[2];  // [H,U]
    const float* w2      = (const float*)d_in[3];  // [H,U]
    const float* vvec    = (const float*)d_in[4];  // [U]
    float* out = (float*)d_out;

    // ws (floats): pqI[131072] | pvI[1048576] | denom[1024] | slab[8*524288]
    float* ws    = (float*)d_ws;
    float* pqI   = ws;
    float* pvI   = pqI + BB * UU * QQ;
    float* denom = pvI + (size_t)BB * UU * VV;
    float* slab  = denom + BB * QQ;

    proj_kernel<<<256 + 32, 256, 0, stream>>>(queries, values, w1, w2, pqI, pvI, denom);
    fused_kernel<<<BB * (QQ / 16) * (VV / 256), 512, 0, stream>>>(pqI, pvI, vvec, values, slab, denom);
    reduce_kernel<<<(BB * QQ * HH) / 4 / 256, 256, 0, stream>>>(slab, denom, out);
}